// Round 1
// baseline (2121.310 us; speedup 1.0000x reference)
//
#include <hip/hip_runtime.h>
#include <hip/hip_bf16.h>
#include <cstdint>
#include <cstddef>

typedef __bf16 bf16_t;
typedef __attribute__((ext_vector_type(8))) __bf16 bf16x8;
typedef __attribute__((ext_vector_type(4))) float floatx4;

// ---------------------------------------------------------------------------
// async global->LDS, 16B per lane. LDS dest is wave-uniform base + lane*16.
// ---------------------------------------------------------------------------
__device__ __forceinline__ void load_lds_16B(const void* g, void* l) {
  __builtin_amdgcn_global_load_lds(
      (__attribute__((address_space(1))) void*)(uintptr_t)g,
      (__attribute__((address_space(3))) void*)l,
      16, 0, 0);
}

// ---------------------------------------------------------------------------
// Pre-pass 1: x fp32 -> bf16  (8 elements / thread)
// ---------------------------------------------------------------------------
__global__ __launch_bounds__(256) void cast_x_kernel(
    const float* __restrict__ in, bf16_t* __restrict__ out, size_t n) {
  size_t i = ((size_t)blockIdx.x * 256 + threadIdx.x) * 8;
  if (i + 8 > n) return;
  const float4* p = (const float4*)(in + i);
  float4 a = p[0], b = p[1];
  bf16x8 v;
  v[0] = (bf16_t)a.x; v[1] = (bf16_t)a.y; v[2] = (bf16_t)a.z; v[3] = (bf16_t)a.w;
  v[4] = (bf16_t)b.x; v[5] = (bf16_t)b.y; v[6] = (bf16_t)b.z; v[7] = (bf16_t)b.w;
  *(bf16x8*)(out + i) = v;
}

// ---------------------------------------------------------------------------
// Pre-pass 2: W fp32 [N,K] * blockscale[(n/128),(k/128)] -> bf16
// grid: x = N rows, y = K/2048 chunks; 8 elems/thread (never crosses k-block)
// ---------------------------------------------------------------------------
__global__ __launch_bounds__(256) void dequant_w_kernel(
    const float* __restrict__ w, const float* __restrict__ s,
    bf16_t* __restrict__ out, int K, int KB) {
  const int row = blockIdx.x;
  const int k = (blockIdx.y * 256 + threadIdx.x) * 8;
  const float sc = s[(row >> 7) * KB + (k >> 7)];
  const size_t i = (size_t)row * K + k;
  const float4* p = (const float4*)(w + i);
  float4 a = p[0], b = p[1];
  bf16x8 v;
  v[0] = (bf16_t)(a.x * sc); v[1] = (bf16_t)(a.y * sc);
  v[2] = (bf16_t)(a.z * sc); v[3] = (bf16_t)(a.w * sc);
  v[4] = (bf16_t)(b.x * sc); v[5] = (bf16_t)(b.y * sc);
  v[6] = (bf16_t)(b.z * sc); v[7] = (bf16_t)(b.w * sc);
  *(bf16x8*)(out + i) = v;
}

// ---------------------------------------------------------------------------
// GEMM: C[M,N] = A[M,K] * B[N,K]^T + bias  (m97-style structure)
// 128x128 tile, BK=32, 256 threads (4 waves), wave computes 64x64 via
// 4x4 grid of mfma_f32_16x16x32_bf16. Staging via global_load_lds x16B.
// ---------------------------------------------------------------------------
#define BM 128
#define BN 128
#define BK 32

__global__ __launch_bounds__(256) void gemm_bt_kernel(
    const bf16_t* __restrict__ A, const bf16_t* __restrict__ B,
    const float* __restrict__ bias, float* __restrict__ C,
    int M, int N, int K) {
  __shared__ __align__(16) bf16_t As[BM * BK];  // [row][k], 64B rows
  __shared__ __align__(16) bf16_t Bs[BN * BK];  // [col][k]

  const int tid  = threadIdx.x;
  const int wave = tid >> 6;
  const int lane = tid & 63;
  const int lm   = lane & 15;   // row (A) / col (B) within 16
  const int quad = lane >> 4;   // k-quad

  const int bm = blockIdx.y;
  const int bn = blockIdx.x;

  // staging map: thread t covers tile-row t/4 (and +64), k = (t&3)*8 .. +7
  const int srow  = tid >> 2;
  const int skoff = (tid & 3) * 8;

  const bf16_t* Ag = A + (size_t)(bm * BM + srow) * K + skoff;
  const bf16_t* Bg = B + (size_t)(bn * BN + srow) * K + skoff;
  const size_t rowK64 = (size_t)64 * K;

  // wave-uniform LDS bases: byte offset t*16 == element t*8
  bf16_t* lA0 = &As[wave * 512];
  bf16_t* lA1 = &As[2048 + wave * 512];
  bf16_t* lB0 = &Bs[wave * 512];
  bf16_t* lB1 = &Bs[2048 + wave * 512];

  const int wm = (wave & 1) * 64;
  const int wn = (wave >> 1) * 64;

  floatx4 acc[4][4] = {};

  for (int k0 = 0; k0 < K; k0 += BK) {
    __syncthreads();  // prior iteration's LDS reads done
    load_lds_16B(Ag + k0, lA0);
    load_lds_16B(Ag + rowK64 + k0, lA1);
    load_lds_16B(Bg + k0, lB0);
    load_lds_16B(Bg + rowK64 + k0, lB1);
    __syncthreads();  // vmcnt(0) drain: staging visible

    bf16x8 af[4], bfr[4];
#pragma unroll
    for (int i = 0; i < 4; ++i) {
      af[i]  = *(const bf16x8*)&As[(wm + i * 16 + lm) * BK + quad * 8];
      bfr[i] = *(const bf16x8*)&Bs[(wn + i * 16 + lm) * BK + quad * 8];
    }
#pragma unroll
    for (int i = 0; i < 4; ++i)
#pragma unroll
      for (int j = 0; j < 4; ++j)
        acc[i][j] =
            __builtin_amdgcn_mfma_f32_16x16x32_bf16(af[i], bfr[j], acc[i][j], 0, 0, 0);
  }

  // epilogue: C/D layout col=lane&15, row=quad*4+r  [m89/m91]
#pragma unroll
  for (int j = 0; j < 4; ++j) {
    const int n = bn * BN + wn + j * 16 + lm;
    const float bv = bias[n];
#pragma unroll
    for (int i = 0; i < 4; ++i) {
      const int m0 = bm * BM + wm + i * 16 + quad * 4;
#pragma unroll
      for (int r = 0; r < 4; ++r) {
        C[(size_t)(m0 + r) * N + n] = acc[i][j][r] + bv;
      }
    }
  }
}

// ---------------------------------------------------------------------------
extern "C" void kernel_launch(void* const* d_in, const int* in_sizes, int n_in,
                              void* d_out, int out_size, void* d_ws, size_t ws_size,
                              hipStream_t stream) {
  const float* x    = (const float*)d_in[0];  // [M,K]
  const float* w    = (const float*)d_in[1];  // [N,K]
  const float* s    = (const float*)d_in[2];  // [N/128, K/128]
  const float* bias = (const float*)d_in[3];  // [N]
  float* out = (float*)d_out;                 // [M,N]

  const int N  = in_sizes[3];
  const int K  = (int)((long long)in_sizes[1] / N);
  const int M  = (int)((long long)in_sizes[0] / K);
  const int KB = K / 128;

  bf16_t* xb = (bf16_t*)d_ws;                 // M*K bf16
  bf16_t* wb = xb + (size_t)M * K;            // N*K bf16

  const size_t nx = (size_t)M * K;
  cast_x_kernel<<<(int)(nx / 2048), 256, 0, stream>>>(x, xb, nx);

  dim3 gw(N, K / 2048);
  dequant_w_kernel<<<gw, 256, 0, stream>>>(w, s, wb, K, KB);

  dim3 grid(N / BN, M / BM);
  gemm_bt_kernel<<<grid, 256, 0, stream>>>(xb, wb, bias, out, M, N, K);
}